// Round 1
// baseline (252.363 us; speedup 1.0000x reference)
//
#include <hip/hip_runtime.h>

typedef unsigned short u16;
typedef __bf16 bf16x8 __attribute__((ext_vector_type(8)));
typedef unsigned short u16x8 __attribute__((ext_vector_type(8)));
typedef float f32x4 __attribute__((ext_vector_type(4)));

#define MFMA16(a, b, c) __builtin_amdgcn_mfma_f32_16x16x32_bf16(a, b, c, 0, 0, 0)

#define GLDS16(gp, lp)                                                         \
  __builtin_amdgcn_global_load_lds(                                            \
      (const __attribute__((address_space(1))) unsigned int*)(gp),             \
      (__attribute__((address_space(3))) unsigned int*)(lp), 16, 0, 0)

__device__ __forceinline__ u16 f2bf(float f) {
  unsigned int u = __builtin_bit_cast(unsigned int, f);
  u += 0x7fffu + ((u >> 16) & 1u);
  return (u16)(u >> 16);
}

// ---------------- elementwise fp32 -> bf16 ----------------
__global__ void convert_x_kernel(const float* __restrict__ src,
                                 u16* __restrict__ dst, int n4) {
  int i = blockIdx.x * 256 + threadIdx.x;
  if (i < n4) {
    float4 v = ((const float4*)src)[i];
    ushort4 o;
    o.x = f2bf(v.x); o.y = f2bf(v.y); o.z = f2bf(v.z); o.w = f2bf(v.w);
    ((ushort4*)dst)[i] = o;
  }
}

// ---------------- transpose fp32 [K][N] -> bf16 [N][K] ----------------
__global__ void transpose_w_kernel(const float* __restrict__ src,
                                   u16* __restrict__ dst, int K, int N) {
  __shared__ float tile[32][33];
  const int n0 = blockIdx.x * 32, k0 = blockIdx.y * 32;
  const int t = threadIdx.x;
  const int r = t >> 3, c = (t & 7) * 4;
  float4 v = *(const float4*)&src[(size_t)(k0 + r) * N + n0 + c];
  tile[r][c + 0] = v.x; tile[r][c + 1] = v.y;
  tile[r][c + 2] = v.z; tile[r][c + 3] = v.w;
  __syncthreads();
  ushort4 o;
  o.x = f2bf(tile[c + 0][r]); o.y = f2bf(tile[c + 1][r]);
  o.z = f2bf(tile[c + 2][r]); o.w = f2bf(tile[c + 3][r]);
  *(ushort4*)&dst[(size_t)(n0 + r) * K + k0 + c] = o;
}

// ---------------- GEMM: A[M][K] bf16 row-major, Bt[N][K] bf16 (B^T) ----------
// MODE 0: qkv epilogue (scatter to Q/K/V head-split, +bias, Q*=1/8, bf16 out)
// MODE 1: proj epilogue (fp32 out[M][N], +bias)
template <int MODE>
__global__ __launch_bounds__(256) void gemm_bt_kernel(
    const u16* __restrict__ A, const u16* __restrict__ Bt,
    const float* __restrict__ bias, float* __restrict__ outF,
    u16* __restrict__ Qo, u16* __restrict__ Ko, u16* __restrict__ Vo,
    int M, int N, int K) {
  __shared__ __align__(16) u16 As[128 * 32];
  __shared__ __align__(16) u16 Bs[128 * 32];
  const int t = threadIdx.x;
  const int lane = t & 63;
  const int l15 = lane & 15, g = lane >> 4;
  const int w = t >> 6, wr = w >> 1, wc = w & 1;
  const int m0 = blockIdx.x * 128, n0 = blockIdx.y * 128;
  const int ar = t >> 2, ak = (t & 3) * 8;
  u16* AsW = As + (t & ~63) * 8;
  u16* BsW = Bs + (t & ~63) * 8;
  const u16* Ag = A + (size_t)(m0 + ar) * K + ak;
  const u16* Bg = Bt + (size_t)(n0 + ar) * K + ak;

  f32x4 acc[4][4] = {};
  for (int k0 = 0; k0 < K; k0 += 32) {
    __syncthreads();
    GLDS16(Ag + k0, AsW);
    GLDS16(Ag + (size_t)64 * K + k0, AsW + 2048);
    GLDS16(Bg + k0, BsW);
    GLDS16(Bg + (size_t)64 * K + k0, BsW + 2048);
    __syncthreads();
    bf16x8 af[4], bfr[4];
#pragma unroll
    for (int i = 0; i < 4; ++i)
      af[i] = *(const bf16x8*)&As[(wr * 64 + i * 16 + l15) * 32 + g * 8];
#pragma unroll
    for (int j = 0; j < 4; ++j)
      bfr[j] = *(const bf16x8*)&Bs[(wc * 64 + j * 16 + l15) * 32 + g * 8];
#pragma unroll
    for (int i = 0; i < 4; ++i)
#pragma unroll
      for (int j = 0; j < 4; ++j)
        acc[i][j] = MFMA16(af[i], bfr[j], acc[i][j]);
  }

#pragma unroll
  for (int j = 0; j < 4; ++j) {
    const int n = n0 + wc * 64 + j * 16 + l15;
    const float bv = bias[n];
#pragma unroll
    for (int i = 0; i < 4; ++i) {
      const int mbase = m0 + wr * 64 + i * 16 + g * 4;
#pragma unroll
      for (int r = 0; r < 4; ++r) {
        const float v = acc[i][j][r] + bv;
        const int m = mbase + r;
        if (MODE == 1) {
          outF[(size_t)m * N + n] = v;
        } else {
          const int part = n >> 10, f = n & 1023;
          const int hh = f >> 6, d = f & 63;
          const int b = m >> 11, s = m & 2047;
          const size_t off = (((size_t)(b * 16 + hh)) * 2048 + s) * 64 + d;
          u16* dst = (part == 0) ? Qo : (part == 1) ? Ko : Vo;
          dst[off] = f2bf(part == 0 ? v * 0.125f : v);
        }
      }
    }
  }
}

// ---------------- flash attention (causal), bf16 MFMA --------------
// grid: (S/64, B*H); block 256 (4 waves x 16 q-rows)
__global__ __launch_bounds__(256) void attn_kernel(
    const u16* __restrict__ Qg, const u16* __restrict__ Kg,
    const u16* __restrict__ Vg, u16* __restrict__ Og) {
  __shared__ __align__(16) u16 Ks[64 * 64];     // XOR-swizzled chunks
  __shared__ __align__(16) u16 Vt[64 * 72];     // transposed [d][kv], +8 pad
  __shared__ __align__(16) u16 Ps[4][16 * 72];  // per-wave P, +8 pad

  const int bx = blockIdx.x;  // q-tile
  const int bh = blockIdx.y;  // b*16+h
  const int t = threadIdx.x;
  const int lane = t & 63, w = t >> 6;
  const int l15 = lane & 15, g = lane >> 4;
  const int q0 = bx * 64;

  const size_t hb = (size_t)bh * (2048 * 64);
  const u16* Qh = Qg + hb;
  const u16* Kh = Kg + hb;
  const u16* Vh = Vg + hb;

  // Q fragments (pre-scaled by 1/8 in the QKV epilogue)
  const int qrow = q0 + w * 16 + l15;
  const bf16x8 qf0 = *(const bf16x8*)(Qh + (size_t)qrow * 64 + g * 8);
  const bf16x8 qf1 = *(const bf16x8*)(Qh + (size_t)qrow * 64 + 32 + g * 8);

  f32x4 oacc[4] = {};
  float mrow[4], lrow[4];
#pragma unroll
  for (int r = 0; r < 4; ++r) { mrow[r] = -1e30f; lrow[r] = 0.f; }

  u16* Pw = &Ps[w][0];
  const int kr = t >> 3;          // staging row 0..31
  const int cs = t & 7;           // store chunk
  const int cl = cs ^ (kr & 7);   // logical chunk (K swizzle)
  u16* KsW = Ks + (t & ~63) * 8;

  const int nt = bx + 1;
  for (int kt = 0; kt < nt; ++kt) {
    const int kv0 = kt * 64;
    __syncthreads();
    // K tile: pre-swizzled global source -> linear LDS dest
    GLDS16(Kh + (size_t)(kv0 + kr) * 64 + cl * 8, KsW);
    GLDS16(Kh + (size_t)(kv0 + 32 + kr) * 64 + cl * 8, KsW + 2048);
    // V tile: transpose to Vt[d][kv] via registers
#pragma unroll
    for (int i = 0; i < 2; ++i) {
      const int kv = i * 32 + kr;
      const int d0 = cs * 8;
      u16x8 v8 = *(const u16x8*)(Vh + (size_t)(kv0 + kv) * 64 + d0);
#pragma unroll
      for (int j = 0; j < 8; ++j) Vt[(d0 + j) * 72 + kv] = v8[j];
    }
    __syncthreads();

    // S = Q K^T : per wave 16 q-rows x 64 kv-cols
    f32x4 sacc[4];
#pragma unroll
    for (int cf = 0; cf < 4; ++cf) {
      const int krow = cf * 16 + l15;
      const int sw = krow & 7;
      const bf16x8 kf0 = *(const bf16x8*)&Ks[krow * 64 + ((g) ^ sw) * 8];
      const bf16x8 kf1 = *(const bf16x8*)&Ks[krow * 64 + ((g + 4) ^ sw) * 8];
      f32x4 z = {0.f, 0.f, 0.f, 0.f};
      z = MFMA16(qf0, kf0, z);
      z = MFMA16(qf1, kf1, z);
      sacc[cf] = z;
    }

    if (kt == bx) {  // diagonal tile: causal mask
#pragma unroll
      for (int cf = 0; cf < 4; ++cf)
#pragma unroll
        for (int r = 0; r < 4; ++r) {
          const int qi = q0 + w * 16 + g * 4 + r;
          const int kj = kv0 + cf * 16 + l15;
          if (kj > qi) sacc[cf][r] = -1e30f;
        }
    }

    // online softmax (row stats shared by 16 lanes of each row)
    float tm[4];
#pragma unroll
    for (int r = 0; r < 4; ++r)
      tm[r] = fmaxf(fmaxf(sacc[0][r], sacc[1][r]),
                    fmaxf(sacc[2][r], sacc[3][r]));
#pragma unroll
    for (int off = 8; off >= 1; off >>= 1)
#pragma unroll
      for (int r = 0; r < 4; ++r)
        tm[r] = fmaxf(tm[r], __shfl_xor(tm[r], off, 16));

    float sc[4];
#pragma unroll
    for (int r = 0; r < 4; ++r) {
      const float mn = fmaxf(mrow[r], tm[r]);
      sc[r] = __expf(mrow[r] - mn);
      mrow[r] = mn;
    }
    float rs[4] = {0.f, 0.f, 0.f, 0.f};
#pragma unroll
    for (int cf = 0; cf < 4; ++cf)
#pragma unroll
      for (int r = 0; r < 4; ++r) {
        const float p = __expf(sacc[cf][r] - mrow[r]);
        rs[r] += p;
        Pw[(g * 4 + r) * 72 + cf * 16 + l15] = f2bf(p);
      }
#pragma unroll
    for (int off = 8; off >= 1; off >>= 1)
#pragma unroll
      for (int r = 0; r < 4; ++r) rs[r] += __shfl_xor(rs[r], off, 16);

    const f32x4 scv = {sc[0], sc[1], sc[2], sc[3]};
#pragma unroll
    for (int r = 0; r < 4; ++r) lrow[r] = lrow[r] * sc[r] + rs[r];
#pragma unroll
    for (int f = 0; f < 4; ++f) oacc[f] *= scv;

    // O += P V
#pragma unroll
    for (int c = 0; c < 2; ++c) {
      const bf16x8 pa = *(const bf16x8*)&Pw[l15 * 72 + c * 32 + g * 8];
#pragma unroll
      for (int f = 0; f < 4; ++f) {
        const bf16x8 vb = *(const bf16x8*)&Vt[(f * 16 + l15) * 72 + c * 32 + g * 8];
        oacc[f] = MFMA16(pa, vb, oacc[f]);
      }
    }
  }

  // write merged-head O[b][s][h*64+d] bf16
  const int b = bh >> 4, h = bh & 15;
#pragma unroll
  for (int f = 0; f < 4; ++f)
#pragma unroll
    for (int r = 0; r < 4; ++r) {
      const int s = q0 + w * 16 + g * 4 + r;
      const float v = oacc[f][r] / lrow[r];
      Og[((size_t)b * 2048 + s) * 1024 + h * 64 + f * 16 + l15] = f2bf(v);
    }
}

extern "C" void kernel_launch(void* const* d_in, const int* in_sizes, int n_in,
                              void* d_out, int out_size, void* d_ws,
                              size_t ws_size, hipStream_t stream) {
  const float* x = (const float*)d_in[0];       // [2,2048,1024]
  const float* w_attn = (const float*)d_in[1];  // [1024,3072]
  const float* b_attn = (const float*)d_in[2];  // [3072]
  const float* w_proj = (const float*)d_in[3];  // [1024,1024]
  const float* b_proj = (const float*)d_in[4];  // [1024]
  float* out = (float*)d_out;                   // [2,2048,1024] fp32

  char* ws = (char*)d_ws;
  u16* xb = (u16*)(ws);                          // 8 MB (reused as O later)
  u16* wT = (u16*)(ws + (8u << 20));             // 6 MB  [3072][1024]
  u16* wpT = (u16*)(ws + (14u << 20));           // 2 MB  [1024][1024]
  u16* Qb = (u16*)(ws + (16u << 20));            // 8 MB  [b][h][s][d]
  u16* Kb = (u16*)(ws + (24u << 20));            // 8 MB
  u16* Vb = (u16*)(ws + (32u << 20));            // 8 MB
  u16* Ob = xb;                                  // reuse xb region

  convert_x_kernel<<<4096, 256, 0, stream>>>(x, xb, 1048576);
  transpose_w_kernel<<<dim3(96, 32), 256, 0, stream>>>(w_attn, wT, 1024, 3072);
  transpose_w_kernel<<<dim3(32, 32), 256, 0, stream>>>(w_proj, wpT, 1024, 1024);

  gemm_bt_kernel<0><<<dim3(32, 24), 256, 0, stream>>>(
      xb, wT, b_attn, nullptr, Qb, Kb, Vb, 4096, 3072, 1024);

  attn_kernel<<<dim3(32, 32), 256, 0, stream>>>(Qb, Kb, Vb, Ob);

  gemm_bt_kernel<1><<<dim3(32, 8), 256, 0, stream>>>(
      Ob, wpT, b_proj, out, nullptr, nullptr, nullptr, 4096, 1024, 1024);
}

// Round 2
// 157.466 us; speedup vs baseline: 1.6027x; 1.6027x over previous
//
#include <hip/hip_runtime.h>

typedef unsigned short u16;
typedef __bf16 bf16x8 __attribute__((ext_vector_type(8)));
typedef unsigned short u16x8 __attribute__((ext_vector_type(8)));
typedef float f32x4 __attribute__((ext_vector_type(4)));

#define MFMA16(a, b, c) __builtin_amdgcn_mfma_f32_16x16x32_bf16(a, b, c, 0, 0, 0)

#define GLDS16(gp, lp)                                                         \
  __builtin_amdgcn_global_load_lds(                                            \
      (const __attribute__((address_space(1))) unsigned int*)(gp),             \
      (__attribute__((address_space(3))) unsigned int*)(lp), 16, 0, 0)

__device__ __forceinline__ u16 f2bf(float f) {
  unsigned int u = __builtin_bit_cast(unsigned int, f);
  u += 0x7fffu + ((u >> 16) & 1u);
  return (u16)(u >> 16);
}

// Q pre-scale: 1/sqrt(64) * log2(e)  (scores produced directly in log2 domain)
#define QSCALE 0.1803368842048386f

// ---------------- elementwise fp32 -> bf16 ----------------
__global__ void convert_x_kernel(const float* __restrict__ src,
                                 u16* __restrict__ dst, int n4) {
  int i = blockIdx.x * 256 + threadIdx.x;
  if (i < n4) {
    float4 v = ((const float4*)src)[i];
    ushort4 o;
    o.x = f2bf(v.x); o.y = f2bf(v.y); o.z = f2bf(v.z); o.w = f2bf(v.w);
    ((ushort4*)dst)[i] = o;
  }
}

// ---------------- transpose fp32 [K][N] -> bf16 [N][K] ----------------
__global__ void transpose_w_kernel(const float* __restrict__ src,
                                   u16* __restrict__ dst, int K, int N) {
  __shared__ float tile[32][33];
  const int n0 = blockIdx.x * 32, k0 = blockIdx.y * 32;
  const int t = threadIdx.x;
  const int r = t >> 3, c = (t & 7) * 4;
  float4 v = *(const float4*)&src[(size_t)(k0 + r) * N + n0 + c];
  tile[r][c + 0] = v.x; tile[r][c + 1] = v.y;
  tile[r][c + 2] = v.z; tile[r][c + 3] = v.w;
  __syncthreads();
  ushort4 o;
  o.x = f2bf(tile[c + 0][r]); o.y = f2bf(tile[c + 1][r]);
  o.z = f2bf(tile[c + 2][r]); o.w = f2bf(tile[c + 3][r]);
  *(ushort4*)&dst[(size_t)(n0 + r) * K + k0 + c] = o;
}

// ---------------- GEMM: A[M][K] bf16 row-major, Bt[N][K] bf16 (B^T) ----------
// MODE 0: qkv epilogue (scatter to Q/K/V head-split, +bias, Q*=QSCALE, bf16)
// MODE 1: proj epilogue (fp32 out[M][N], +bias)
template <int MODE>
__global__ __launch_bounds__(256) void gemm_bt_kernel(
    const u16* __restrict__ A, const u16* __restrict__ Bt,
    const float* __restrict__ bias, float* __restrict__ outF,
    u16* __restrict__ Qo, u16* __restrict__ Ko, u16* __restrict__ Vo,
    int M, int N, int K) {
  __shared__ __align__(16) u16 As[128 * 32];
  __shared__ __align__(16) u16 Bs[128 * 32];
  const int t = threadIdx.x;
  const int lane = t & 63;
  const int l15 = lane & 15, g = lane >> 4;
  const int w = t >> 6, wr = w >> 1, wc = w & 1;
  const int m0 = blockIdx.x * 128, n0 = blockIdx.y * 128;
  const int ar = t >> 2, ak = (t & 3) * 8;
  u16* AsW = As + (t & ~63) * 8;
  u16* BsW = Bs + (t & ~63) * 8;
  const u16* Ag = A + (size_t)(m0 + ar) * K + ak;
  const u16* Bg = Bt + (size_t)(n0 + ar) * K + ak;

  f32x4 acc[4][4] = {};
  for (int k0 = 0; k0 < K; k0 += 32) {
    __syncthreads();
    GLDS16(Ag + k0, AsW);
    GLDS16(Ag + (size_t)64 * K + k0, AsW + 2048);
    GLDS16(Bg + k0, BsW);
    GLDS16(Bg + (size_t)64 * K + k0, BsW + 2048);
    __syncthreads();
    bf16x8 af[4], bfr[4];
#pragma unroll
    for (int i = 0; i < 4; ++i)
      af[i] = *(const bf16x8*)&As[(wr * 64 + i * 16 + l15) * 32 + g * 8];
#pragma unroll
    for (int j = 0; j < 4; ++j)
      bfr[j] = *(const bf16x8*)&Bs[(wc * 64 + j * 16 + l15) * 32 + g * 8];
#pragma unroll
    for (int i = 0; i < 4; ++i)
#pragma unroll
      for (int j = 0; j < 4; ++j)
        acc[i][j] = MFMA16(af[i], bfr[j], acc[i][j]);
  }

#pragma unroll
  for (int j = 0; j < 4; ++j) {
    const int n = n0 + wc * 64 + j * 16 + l15;
    const float bv = bias[n];
#pragma unroll
    for (int i = 0; i < 4; ++i) {
      const int mbase = m0 + wr * 64 + i * 16 + g * 4;
#pragma unroll
      for (int r = 0; r < 4; ++r) {
        const float v = acc[i][j][r] + bv;
        const int m = mbase + r;
        if (MODE == 1) {
          outF[(size_t)m * N + n] = v;
        } else {
          const int part = n >> 10, f = n & 1023;
          const int hh = f >> 6, d = f & 63;
          const int b = m >> 11, s = m & 2047;
          const size_t off = (((size_t)(b * 16 + hh)) * 2048 + s) * 64 + d;
          u16* dst = (part == 0) ? Qo : (part == 1) ? Ko : Vo;
          dst[off] = f2bf(part == 0 ? v * QSCALE : v);
        }
      }
    }
  }
}

// ---------------- flash attention (causal), bf16 MFMA --------------
// grid: (16, B*H); block 256 (4 waves x 16 q-rows). Each block does the
// q-tile pair {p, 31-p} -> exactly 33 kv-tile iterations per block.
// Double-buffered K (LDS, XOR-swizzled chunks) and V^T (LDS, kv-chunk
// XOR-swizzled by d>>3); K staged via global_load_lds, V via registers,
// both issued one tile ahead so staging hides under compute.
__global__ __launch_bounds__(256) void attn_kernel(
    const u16* __restrict__ Qg, const u16* __restrict__ Kg,
    const u16* __restrict__ Vg, u16* __restrict__ Og) {
  __shared__ __align__(16) u16 Ks[2][64 * 64];
  __shared__ __align__(16) u16 Vt[2][64 * 72];
  __shared__ __align__(16) u16 Ps[4][16 * 72];

  const int pp = blockIdx.x;  // pair index 0..15
  const int bh = blockIdx.y;  // b*16+h
  const int t = threadIdx.x;
  const int lane = t & 63, w = t >> 6;
  const int l15 = lane & 15, g = lane >> 4;

  const size_t hb = (size_t)bh * (2048 * 64);
  const u16* Qh = Qg + hb;
  const u16* Kh = Kg + hb;
  const u16* Vh = Vg + hb;
  const int b = bh >> 4, h = bh & 15;

  const int kr = t >> 3;         // staging row 8w..8w+7
  const int cs = t & 7;          // staging chunk slot
  const int cl = cs ^ (kr & 7);  // K swizzle: logical chunk for this slot
  u16* Pw = &Ps[w][0];

  for (int half = 0; half < 2; ++half) {
    const int bx = half ? (31 - pp) : pp;
    const int q0 = bx * 64;
    const int nt = bx + 1;

    const int qrow = q0 + w * 16 + l15;
    const bf16x8 qf0 = *(const bf16x8*)(Qh + (size_t)qrow * 64 + g * 8);
    const bf16x8 qf1 = *(const bf16x8*)(Qh + (size_t)qrow * 64 + 32 + g * 8);

    f32x4 oacc[4] = {};
    float mrow[4], lrow[4];
#pragma unroll
    for (int r = 0; r < 4; ++r) { mrow[r] = -1e30f; lrow[r] = 0.f; }

    // ---- prologue: stage tile 0 ----
    u16x8 vpre[2];
    {
      u16* KsW = &Ks[0][(t & ~63) * 8];
      GLDS16(Kh + (size_t)kr * 64 + cl * 8, KsW);
      GLDS16(Kh + (size_t)(32 + kr) * 64 + cl * 8, KsW + 2048);
      vpre[0] = *(const u16x8*)(Vh + (size_t)kr * 64 + cs * 8);
      vpre[1] = *(const u16x8*)(Vh + (size_t)(32 + kr) * 64 + cs * 8);
    }
    __syncthreads();  // drains vmcnt: K in LDS, V in regs
#pragma unroll
    for (int i = 0; i < 2; ++i) {
      const int col = ((i * 32 + kr) ^ (cs << 3));
#pragma unroll
      for (int j = 0; j < 8; ++j) Vt[0][(cs * 8 + j) * 72 + col] = vpre[i][j];
    }
    __syncthreads();

    for (int kt = 0; kt < nt; ++kt) {
      const int cur = kt & 1, nxt = cur ^ 1;
      const bool pf = (kt + 1 < nt);
      if (pf) {  // issue next tile's staging; hides under compute below
        const int kv0n = (kt + 1) * 64;
        u16* KsW = &Ks[nxt][(t & ~63) * 8];
        GLDS16(Kh + (size_t)(kv0n + kr) * 64 + cl * 8, KsW);
        GLDS16(Kh + (size_t)(kv0n + 32 + kr) * 64 + cl * 8, KsW + 2048);
        vpre[0] = *(const u16x8*)(Vh + (size_t)(kv0n + kr) * 64 + cs * 8);
        vpre[1] = *(const u16x8*)(Vh + (size_t)(kv0n + 32 + kr) * 64 + cs * 8);
      }

      // S = Q K^T (scores in log2 domain; Q pre-scaled by 1/8*log2e)
      f32x4 sacc[4];
#pragma unroll
      for (int cf = 0; cf < 4; ++cf) {
        const int krow = cf * 16 + l15;
        const int sw = krow & 7;
        const bf16x8 kf0 = *(const bf16x8*)&Ks[cur][krow * 64 + (g ^ sw) * 8];
        const bf16x8 kf1 =
            *(const bf16x8*)&Ks[cur][krow * 64 + ((g + 4) ^ sw) * 8];
        f32x4 z = {0.f, 0.f, 0.f, 0.f};
        z = MFMA16(qf0, kf0, z);
        z = MFMA16(qf1, kf1, z);
        sacc[cf] = z;
      }

      if (kt == bx) {  // diagonal tile: causal mask
        const int kv0 = kt * 64;
#pragma unroll
        for (int cf = 0; cf < 4; ++cf)
#pragma unroll
          for (int r = 0; r < 4; ++r) {
            const int qi = q0 + w * 16 + g * 4 + r;
            const int kj = kv0 + cf * 16 + l15;
            if (kj > qi) sacc[cf][r] = -1e30f;
          }
      }

      // online softmax (16 lanes share a q-row's stats)
      float tm[4];
#pragma unroll
      for (int r = 0; r < 4; ++r)
        tm[r] = fmaxf(fmaxf(sacc[0][r], sacc[1][r]),
                      fmaxf(sacc[2][r], sacc[3][r]));
#pragma unroll
      for (int off = 8; off >= 1; off >>= 1)
#pragma unroll
        for (int r = 0; r < 4; ++r)
          tm[r] = fmaxf(tm[r], __shfl_xor(tm[r], off, 16));

      float sc[4];
#pragma unroll
      for (int r = 0; r < 4; ++r) {
        const float mn = fmaxf(mrow[r], tm[r]);
        sc[r] = exp2f(mrow[r] - mn);
        mrow[r] = mn;
      }
      float rs[4] = {0.f, 0.f, 0.f, 0.f};
#pragma unroll
      for (int cf = 0; cf < 4; ++cf)
#pragma unroll
        for (int r = 0; r < 4; ++r) {
          const float p = exp2f(sacc[cf][r] - mrow[r]);
          rs[r] += p;
          Pw[(g * 4 + r) * 72 + cf * 16 + l15] = f2bf(p);
        }
#pragma unroll
      for (int off = 8; off >= 1; off >>= 1)
#pragma unroll
        for (int r = 0; r < 4; ++r) rs[r] += __shfl_xor(rs[r], off, 16);

      const f32x4 scv = {sc[0], sc[1], sc[2], sc[3]};
#pragma unroll
      for (int r = 0; r < 4; ++r) lrow[r] = lrow[r] * sc[r] + rs[r];
#pragma unroll
      for (int f = 0; f < 4; ++f) oacc[f] *= scv;

      // O += P V   (Vt swizzled: element (d,kv) at [d*72 + (kv ^ ((d>>3)<<3))])
#pragma unroll
      for (int c = 0; c < 2; ++c) {
        const bf16x8 pa = *(const bf16x8*)&Pw[l15 * 72 + c * 32 + g * 8];
#pragma unroll
        for (int f = 0; f < 4; ++f) {
          const int d = f * 16 + l15;
          const int csw = (c * 32 + g * 8) ^ (((d >> 3) & 7) << 3);
          const bf16x8 vb = *(const bf16x8*)&Vt[cur][d * 72 + csw];
          oacc[f] = MFMA16(pa, vb, oacc[f]);
        }
      }

      if (pf) {
        __syncthreads();  // all waves done reading Ks/Vt[cur]; vmcnt drained
#pragma unroll
        for (int i = 0; i < 2; ++i) {
          const int col = ((i * 32 + kr) ^ (cs << 3));
#pragma unroll
          for (int j = 0; j < 8; ++j)
            Vt[nxt][(cs * 8 + j) * 72 + col] = vpre[i][j];
        }
        __syncthreads();  // Vt[nxt] visible
      }
    }

    // write merged-head O[b][s][h*64+d] bf16
#pragma unroll
    for (int f = 0; f < 4; ++f)
#pragma unroll
      for (int r = 0; r < 4; ++r) {
        const int s = q0 + w * 16 + g * 4 + r;
        const float v = oacc[f][r] / lrow[r];
        Og[((size_t)b * 2048 + s) * 1024 + h * 64 + f * 16 + l15] = f2bf(v);
      }
    __syncthreads();  // protect buffers before next half's restaging
  }
}

extern "C" void kernel_launch(void* const* d_in, const int* in_sizes, int n_in,
                              void* d_out, int out_size, void* d_ws,
                              size_t ws_size, hipStream_t stream) {
  const float* x = (const float*)d_in[0];       // [2,2048,1024]
  const float* w_attn = (const float*)d_in[1];  // [1024,3072]
  const float* b_attn = (const float*)d_in[2];  // [3072]
  const float* w_proj = (const float*)d_in[3];  // [1024,1024]
  const float* b_proj = (const float*)d_in[4];  // [1024]
  float* out = (float*)d_out;                   // [2,2048,1024] fp32

  char* ws = (char*)d_ws;
  u16* xb = (u16*)(ws);                          // 8 MB (reused as O later)
  u16* wT = (u16*)(ws + (8u << 20));             // 6 MB  [3072][1024]
  u16* wpT = (u16*)(ws + (14u << 20));           // 2 MB  [1024][1024]
  u16* Qb = (u16*)(ws + (16u << 20));            // 8 MB  [b][h][s][d]
  u16* Kb = (u16*)(ws + (24u << 20));            // 8 MB
  u16* Vb = (u16*)(ws + (32u << 20));            // 8 MB
  u16* Ob = xb;                                  // reuse xb region

  convert_x_kernel<<<4096, 256, 0, stream>>>(x, xb, 1048576);
  transpose_w_kernel<<<dim3(96, 32), 256, 0, stream>>>(w_attn, wT, 1024, 3072);
  transpose_w_kernel<<<dim3(32, 32), 256, 0, stream>>>(w_proj, wpT, 1024, 1024);

  gemm_bt_kernel<0><<<dim3(32, 24), 256, 0, stream>>>(
      xb, wT, b_attn, nullptr, Qb, Kb, Vb, 4096, 3072, 1024);

  attn_kernel<<<dim3(16, 32), 256, 0, stream>>>(Qb, Kb, Vb, Ob);

  gemm_bt_kernel<1><<<dim3(32, 8), 256, 0, stream>>>(
      Ob, wpT, b_proj, out, nullptr, nullptr, nullptr, 4096, 1024, 1024);
}

// Round 4
// 133.229 us; speedup vs baseline: 1.8942x; 1.1819x over previous
//
#include <hip/hip_runtime.h>

typedef unsigned short u16;
typedef __bf16 bf16x8 __attribute__((ext_vector_type(8)));
typedef __bf16 bf16x2 __attribute__((ext_vector_type(2)));
typedef unsigned short u16x8 __attribute__((ext_vector_type(8)));
typedef float f32x4 __attribute__((ext_vector_type(4)));
typedef int i32x4 __attribute__((ext_vector_type(4)));

#define MFMA16(a, b, c) __builtin_amdgcn_mfma_f32_16x16x32_bf16(a, b, c, 0, 0, 0)

#define GLDS16(gp, lp)                                                         \
  __builtin_amdgcn_global_load_lds(                                            \
      (const __attribute__((address_space(1))) unsigned int*)(gp),             \
      (__attribute__((address_space(3))) unsigned int*)(lp), 16, 0, 0)

__device__ __forceinline__ u16 f2bf(float f) {
  unsigned int u = __builtin_bit_cast(unsigned int, f);
  u += 0x7fffu + ((u >> 16) & 1u);
  return (u16)(u >> 16);
}

// Q pre-scale: 1/sqrt(64) * log2(e)  (scores produced directly in log2 domain)
#define QSCALE 0.1803368842048386f

// ---------------- elementwise fp32 -> bf16 ----------------
__global__ void convert_x_kernel(const float* __restrict__ src,
                                 u16* __restrict__ dst, int n4) {
  int i = blockIdx.x * 256 + threadIdx.x;
  if (i < n4) {
    float4 v = ((const float4*)src)[i];
    ushort4 o;
    o.x = f2bf(v.x); o.y = f2bf(v.y); o.z = f2bf(v.z); o.w = f2bf(v.w);
    ((ushort4*)dst)[i] = o;
  }
}

// ---------------- transpose fp32 [K][N] -> bf16 [N][K] ----------------
__global__ void transpose_w_kernel(const float* __restrict__ src,
                                   u16* __restrict__ dst, int K, int N) {
  __shared__ float tile[32][33];
  const int n0 = blockIdx.x * 32, k0 = blockIdx.y * 32;
  const int t = threadIdx.x;
  const int r = t >> 3, c = (t & 7) * 4;
  float4 v = *(const float4*)&src[(size_t)(k0 + r) * N + n0 + c];
  tile[r][c + 0] = v.x; tile[r][c + 1] = v.y;
  tile[r][c + 2] = v.z; tile[r][c + 3] = v.w;
  __syncthreads();
  ushort4 o;
  o.x = f2bf(tile[c + 0][r]); o.y = f2bf(tile[c + 1][r]);
  o.z = f2bf(tile[c + 2][r]); o.w = f2bf(tile[c + 3][r]);
  *(ushort4*)&dst[(size_t)(n0 + r) * K + k0 + c] = o;
}

// ---------------- GEMM: A[M][K] bf16 row-major, Bt[N][K] bf16 (B^T) ----------
// MODE 0: qkv epilogue (scatter to Q/K/V head-split, +bias, Q*=QSCALE, bf16)
// MODE 1: proj epilogue (fp32 out[M][N], +bias)
template <int MODE>
__global__ __launch_bounds__(256) void gemm_bt_kernel(
    const u16* __restrict__ A, const u16* __restrict__ Bt,
    const float* __restrict__ bias, float* __restrict__ outF,
    u16* __restrict__ Qo, u16* __restrict__ Ko, u16* __restrict__ Vo,
    int M, int N, int K) {
  __shared__ __align__(16) u16 As[128 * 32];
  __shared__ __align__(16) u16 Bs[128 * 32];
  const int t = threadIdx.x;
  const int lane = t & 63;
  const int l15 = lane & 15, g = lane >> 4;
  const int w = t >> 6, wr = w >> 1, wc = w & 1;
  const int m0 = blockIdx.x * 128, n0 = blockIdx.y * 128;
  const int ar = t >> 2, ak = (t & 3) * 8;
  u16* AsW = As + (t & ~63) * 8;
  u16* BsW = Bs + (t & ~63) * 8;
  const u16* Ag = A + (size_t)(m0 + ar) * K + ak;
  const u16* Bg = Bt + (size_t)(n0 + ar) * K + ak;

  f32x4 acc[4][4] = {};
  for (int k0 = 0; k0 < K; k0 += 32) {
    __syncthreads();
    GLDS16(Ag + k0, AsW);
    GLDS16(Ag + (size_t)64 * K + k0, AsW + 2048);
    GLDS16(Bg + k0, BsW);
    GLDS16(Bg + (size_t)64 * K + k0, BsW + 2048);
    __syncthreads();
    bf16x8 af[4], bfr[4];
#pragma unroll
    for (int i = 0; i < 4; ++i)
      af[i] = *(const bf16x8*)&As[(wr * 64 + i * 16 + l15) * 32 + g * 8];
#pragma unroll
    for (int j = 0; j < 4; ++j)
      bfr[j] = *(const bf16x8*)&Bs[(wc * 64 + j * 16 + l15) * 32 + g * 8];
#pragma unroll
    for (int i = 0; i < 4; ++i)
#pragma unroll
      for (int j = 0; j < 4; ++j)
        acc[i][j] = MFMA16(af[i], bfr[j], acc[i][j]);
  }

#pragma unroll
  for (int j = 0; j < 4; ++j) {
    const int n = n0 + wc * 64 + j * 16 + l15;
    const float bv = bias[n];
#pragma unroll
    for (int i = 0; i < 4; ++i) {
      const int mbase = m0 + wr * 64 + i * 16 + g * 4;
#pragma unroll
      for (int r = 0; r < 4; ++r) {
        const float v = acc[i][j][r] + bv;
        const int m = mbase + r;
        if (MODE == 1) {
          outF[(size_t)m * N + n] = v;
        } else {
          const int part = n >> 10, f = n & 1023;
          const int hh = f >> 6, d = f & 63;
          const int b = m >> 11, s = m & 2047;
          const size_t off = (((size_t)(b * 16 + hh)) * 2048 + s) * 64 + d;
          u16* dst = (part == 0) ? Qo : (part == 1) ? Ko : Vo;
          dst[off] = f2bf(part == 0 ? v * QSCALE : v);
        }
      }
    }
  }
}

// ---------------- flash attention (causal), bf16 MFMA --------------
// grid: (B*H, 16); block 256 (4 waves x 16 q-rows); q-tile pair {p, 31-p}.
// Swapped QK^T (S^T = K Q^T) so each lane owns one q-row's kv values:
// softmax is in-lane + 2 shuffles, P converted in-register and
// redistributed to the PV B-fragment via ds_bpermute (fetch both cf
// candidates, post-select by dest ghi). PV computes O^T = V^T P^T.
__global__ __launch_bounds__(256) void attn_kernel(
    const u16* __restrict__ Qg, const u16* __restrict__ Kg,
    const u16* __restrict__ Vg, u16* __restrict__ Og) {
  __shared__ __align__(16) u16 Ks[2][64 * 64];
  __shared__ __align__(16) u16 Vt[2][64 * 72];

  const int bh = blockIdx.x;  // b*16+h  (grid.x so same-head blocks share XCD)
  const int pp = blockIdx.y;  // pair index 0..15
  const int t = threadIdx.x;
  const int lane = t & 63, w = t >> 6;
  const int l15 = lane & 15, g = (lane >> 4) & 3;
  const bool ghi = (lane & 32) != 0;  // dest g>>1
  // ds_bpermute source-lane byte addresses (source g' = 2(g&1) + (jj>>1))
  const int addrA = (l15 + 16 * ((2 * g) & 3)) << 2;      // for jj<2
  const int addrB = (l15 + 16 * ((2 * g + 1) & 3)) << 2;  // for jj>=2

  const size_t hb = (size_t)bh * (2048 * 64);
  const u16* Qh = Qg + hb;
  const u16* Kh = Kg + hb;
  const u16* Vh = Vg + hb;
  const int b = bh >> 4, h = bh & 15;

  const int kr = t >> 3;         // staging row 8w..8w+7
  const int cs = t & 7;          // staging chunk slot
  const int cl = cs ^ (kr & 7);  // K swizzle: logical chunk for this slot

  for (int half = 0; half < 2; ++half) {
    const int bx = half ? (31 - pp) : pp;
    const int q0 = bx * 64;
    const int nt = bx + 1;

    const int qrow = q0 + w * 16 + l15;
    const bf16x8 qf0 = *(const bf16x8*)(Qh + (size_t)qrow * 64 + g * 8);
    const bf16x8 qf1 = *(const bf16x8*)(Qh + (size_t)qrow * 64 + 32 + g * 8);

    f32x4 oacc[4] = {};
    float mrow = -1e30f, lrow = 0.f;

    // ---- prologue: stage tile 0 ----
    u16x8 vpre[2];
    {
      u16* KsW = &Ks[0][(t & ~63) * 8];
      GLDS16(Kh + (size_t)kr * 64 + cl * 8, KsW);
      GLDS16(Kh + (size_t)(32 + kr) * 64 + cl * 8, KsW + 2048);
      vpre[0] = *(const u16x8*)(Vh + (size_t)kr * 64 + cs * 8);
      vpre[1] = *(const u16x8*)(Vh + (size_t)(32 + kr) * 64 + cs * 8);
    }
    __syncthreads();  // drains vmcnt: K in LDS, V in regs
#pragma unroll
    for (int i = 0; i < 2; ++i) {
      const int col = ((i * 32 + kr) ^ (cs << 3));
#pragma unroll
      for (int j = 0; j < 8; ++j) Vt[0][(cs * 8 + j) * 72 + col] = vpre[i][j];
    }
    __syncthreads();

    for (int kt = 0; kt < nt; ++kt) {
      const int cur = kt & 1, nxt = cur ^ 1;
      const bool pf = (kt + 1 < nt);
      if (pf) {  // issue next tile's staging; hides under compute below
        const int kv0n = (kt + 1) * 64;
        u16* KsW = &Ks[nxt][(t & ~63) * 8];
        GLDS16(Kh + (size_t)(kv0n + kr) * 64 + cl * 8, KsW);
        GLDS16(Kh + (size_t)(kv0n + 32 + kr) * 64 + cl * 8, KsW + 2048);
        vpre[0] = *(const u16x8*)(Vh + (size_t)(kv0n + kr) * 64 + cs * 8);
        vpre[1] = *(const u16x8*)(Vh + (size_t)(kv0n + 32 + kr) * 64 + cs * 8);
      }

      // S^T = K Q^T : lane holds S[q=qrow][kv = cf*16 + g*4 + r]
      f32x4 sacc[4];
#pragma unroll
      for (int cf = 0; cf < 4; ++cf) {
        const int krow = cf * 16 + l15;
        const int sw = krow & 7;
        const bf16x8 kf0 = *(const bf16x8*)&Ks[cur][krow * 64 + (g ^ sw) * 8];
        const bf16x8 kf1 =
            *(const bf16x8*)&Ks[cur][krow * 64 + ((g + 4) ^ sw) * 8];
        f32x4 z = {0.f, 0.f, 0.f, 0.f};
        z = MFMA16(kf0, qf0, z);
        z = MFMA16(kf1, qf1, z);
        sacc[cf] = z;
      }

      if (kt == bx) {  // diagonal tile: causal mask
        const int kv0 = kt * 64;
#pragma unroll
        for (int cf = 0; cf < 4; ++cf)
#pragma unroll
          for (int r = 0; r < 4; ++r) {
            const int kj = kv0 + cf * 16 + g * 4 + r;
            if (kj > qrow) sacc[cf][r] = -1e30f;
          }
      }

      // online softmax: all 16 kv values for q=qrow are in-lane
      float tm = -1e30f;
#pragma unroll
      for (int cf = 0; cf < 4; ++cf)
#pragma unroll
        for (int r = 0; r < 4; ++r) tm = fmaxf(tm, sacc[cf][r]);
      tm = fmaxf(tm, __shfl_xor(tm, 16));
      tm = fmaxf(tm, __shfl_xor(tm, 32));

      const float mn = fmaxf(mrow, tm);
      const float sc = __builtin_amdgcn_exp2f(mrow - mn);
      mrow = mn;

      float rs = 0.f;
#pragma unroll
      for (int cf = 0; cf < 4; ++cf)
#pragma unroll
        for (int r = 0; r < 4; ++r) {
          const float p = __builtin_amdgcn_exp2f(sacc[cf][r] - mrow);
          sacc[cf][r] = p;
          rs += p;
        }
      rs += __shfl_xor(rs, 16);
      rs += __shfl_xor(rs, 32);
      lrow = lrow * sc + rs;

      // pack P to bf16 pairs: pk[cf][s] covers kv = 16cf + 4g + 2s + {0,1}
      int pk[4][2];
#pragma unroll
      for (int cf = 0; cf < 4; ++cf)
#pragma unroll
        for (int s = 0; s < 2; ++s) {
          bf16x2 tp = {(__bf16)sacc[cf][2 * s], (__bf16)sacc[cf][2 * s + 1]};
          pk[cf][s] = __builtin_bit_cast(int, tp);
        }

      // redistribute to PV B-frag: bfr[c][jj] = kv pair 32c + 8g + 2jj.
      // Dest lane needs register pk[2c + (dest g>>1)][jj&1] of source lane
      // g' = 2(g&1)+(jj>>1). ds_bpermute returns the SOURCE lane's register,
      // so fetch both cf candidates and post-select with the dest's ghi.
      int bfr[2][4];
#pragma unroll
      for (int c = 0; c < 2; ++c)
#pragma unroll
        for (int jj = 0; jj < 4; ++jj) {
          const int addr = (jj >> 1) ? addrB : addrA;
          const int vlo =
              __builtin_amdgcn_ds_bpermute(addr, pk[2 * c][jj & 1]);
          const int vhi =
              __builtin_amdgcn_ds_bpermute(addr, pk[2 * c + 1][jj & 1]);
          bfr[c][jj] = ghi ? vhi : vlo;
        }

#pragma unroll
      for (int f = 0; f < 4; ++f) oacc[f] *= sc;

      // O^T += V^T P^T
#pragma unroll
      for (int c = 0; c < 2; ++c) {
        const i32x4 bb = {bfr[c][0], bfr[c][1], bfr[c][2], bfr[c][3]};
        const bf16x8 pb = __builtin_bit_cast(bf16x8, bb);
#pragma unroll
        for (int f = 0; f < 4; ++f) {
          const int d = f * 16 + l15;
          const int csw = (c * 32 + g * 8) ^ (((d >> 3) & 7) << 3);
          const bf16x8 va = *(const bf16x8*)&Vt[cur][d * 72 + csw];
          oacc[f] = MFMA16(va, pb, oacc[f]);
        }
      }

      if (pf) {
        __syncthreads();  // all waves done reading Ks/Vt[cur]; vmcnt drained
#pragma unroll
        for (int i = 0; i < 2; ++i) {
          const int col = ((i * 32 + kr) ^ (cs << 3));
#pragma unroll
          for (int j = 0; j < 8; ++j)
            Vt[nxt][(cs * 8 + j) * 72 + col] = vpre[i][j];
        }
        __syncthreads();  // Vt[nxt] visible
      }
    }

    // write merged-head O[b][s][h*64 + d], d = f*16 + g*4 + r
    const float inv = 1.f / lrow;
#pragma unroll
    for (int f = 0; f < 4; ++f) {
      ushort4 o;
      o.x = __builtin_bit_cast(u16, (__bf16)(oacc[f][0] * inv));
      o.y = __builtin_bit_cast(u16, (__bf16)(oacc[f][1] * inv));
      o.z = __builtin_bit_cast(u16, (__bf16)(oacc[f][2] * inv));
      o.w = __builtin_bit_cast(u16, (__bf16)(oacc[f][3] * inv));
      *(ushort4*)&Og[((size_t)b * 2048 + qrow) * 1024 + h * 64 + f * 16 +
                     g * 4] = o;
    }
    __syncthreads();  // protect buffers before next half's restaging
  }
}

extern "C" void kernel_launch(void* const* d_in, const int* in_sizes, int n_in,
                              void* d_out, int out_size, void* d_ws,
                              size_t ws_size, hipStream_t stream) {
  const float* x = (const float*)d_in[0];       // [2,2048,1024]
  const float* w_attn = (const float*)d_in[1];  // [1024,3072]
  const float* b_attn = (const float*)d_in[2];  // [3072]
  const float* w_proj = (const float*)d_in[3];  // [1024,1024]
  const float* b_proj = (const float*)d_in[4];  // [1024]
  float* out = (float*)d_out;                   // [2,2048,1024] fp32

  char* ws = (char*)d_ws;
  u16* xb = (u16*)(ws);                          // 8 MB (reused as O later)
  u16* wT = (u16*)(ws + (8u << 20));             // 6 MB  [3072][1024]
  u16* wpT = (u16*)(ws + (14u << 20));           // 2 MB  [1024][1024]
  u16* Qb = (u16*)(ws + (16u << 20));            // 8 MB  [b][h][s][d]
  u16* Kb = (u16*)(ws + (24u << 20));            // 8 MB
  u16* Vb = (u16*)(ws + (32u << 20));            // 8 MB
  u16* Ob = xb;                                  // reuse xb region

  convert_x_kernel<<<4096, 256, 0, stream>>>(x, xb, 1048576);
  transpose_w_kernel<<<dim3(96, 32), 256, 0, stream>>>(w_attn, wT, 1024, 3072);
  transpose_w_kernel<<<dim3(32, 32), 256, 0, stream>>>(w_proj, wpT, 1024, 1024);

  gemm_bt_kernel<0><<<dim3(32, 24), 256, 0, stream>>>(
      xb, wT, b_attn, nullptr, Qb, Kb, Vb, 4096, 3072, 1024);

  attn_kernel<<<dim3(32, 16), 256, 0, stream>>>(Qb, Kb, Vb, Ob);

  gemm_bt_kernel<1><<<dim3(32, 8), 256, 0, stream>>>(
      Ob, wpT, b_proj, out, nullptr, nullptr, nullptr, 4096, 1024, 1024);
}

// Round 5
// 125.391 us; speedup vs baseline: 2.0126x; 1.0625x over previous
//
#include <hip/hip_runtime.h>

typedef unsigned short u16;
typedef __bf16 bf16x8 __attribute__((ext_vector_type(8)));
typedef __bf16 bf16x2 __attribute__((ext_vector_type(2)));
typedef unsigned short u16x8 __attribute__((ext_vector_type(8)));
typedef float f32x4 __attribute__((ext_vector_type(4)));
typedef int i32x4 __attribute__((ext_vector_type(4)));

#define MFMA16(a, b, c) __builtin_amdgcn_mfma_f32_16x16x32_bf16(a, b, c, 0, 0, 0)

#define GLDS16(gp, lp)                                                         \
  __builtin_amdgcn_global_load_lds(                                            \
      (const __attribute__((address_space(1))) unsigned int*)(gp),             \
      (__attribute__((address_space(3))) unsigned int*)(lp), 16, 0, 0)

__device__ __forceinline__ u16 f2bf(float f) {
  unsigned int u = __builtin_bit_cast(unsigned int, f);
  u += 0x7fffu + ((u >> 16) & 1u);
  return (u16)(u >> 16);
}

// Q pre-scale: 1/sqrt(64) * log2(e)  (scores produced directly in log2 domain)
#define QSCALE 0.1803368842048386f

// ---------------- elementwise fp32 -> bf16 ----------------
__global__ void convert_x_kernel(const float* __restrict__ src,
                                 u16* __restrict__ dst, int n4) {
  int i = blockIdx.x * 256 + threadIdx.x;
  if (i < n4) {
    float4 v = ((const float4*)src)[i];
    ushort4 o;
    o.x = f2bf(v.x); o.y = f2bf(v.y); o.z = f2bf(v.z); o.w = f2bf(v.w);
    ((ushort4*)dst)[i] = o;
  }
}

// ---------------- transpose fp32 [K][N] -> bf16 [N][K] ----------------
__global__ void transpose_w_kernel(const float* __restrict__ src,
                                   u16* __restrict__ dst, int K, int N) {
  __shared__ float tile[32][33];
  const int n0 = blockIdx.x * 32, k0 = blockIdx.y * 32;
  const int t = threadIdx.x;
  const int r = t >> 3, c = (t & 7) * 4;
  float4 v = *(const float4*)&src[(size_t)(k0 + r) * N + n0 + c];
  tile[r][c + 0] = v.x; tile[r][c + 1] = v.y;
  tile[r][c + 2] = v.z; tile[r][c + 3] = v.w;
  __syncthreads();
  ushort4 o;
  o.x = f2bf(tile[c + 0][r]); o.y = f2bf(tile[c + 1][r]);
  o.z = f2bf(tile[c + 2][r]); o.w = f2bf(tile[c + 3][r]);
  *(ushort4*)&dst[(size_t)(n0 + r) * K + k0 + c] = o;
}

// ---------------- GEMM 128x128: A[M][K] bf16 rm, Bt[N][K] bf16 (B^T) --------
// qkv epilogue: scatter to Q/K/V head-split, +bias, Q*=QSCALE, bf16 out
__global__ __launch_bounds__(256) void gemm_qkv_kernel(
    const u16* __restrict__ A, const u16* __restrict__ Bt,
    const float* __restrict__ bias, u16* __restrict__ Qo,
    u16* __restrict__ Ko, u16* __restrict__ Vo, int K) {
  __shared__ __align__(16) u16 As[128 * 32];
  __shared__ __align__(16) u16 Bs[128 * 32];
  const int t = threadIdx.x;
  const int lane = t & 63;
  const int l15 = lane & 15, g = lane >> 4;
  const int w = t >> 6, wr = w >> 1, wc = w & 1;
  const int m0 = blockIdx.x * 128, n0 = blockIdx.y * 128;
  const int ar = t >> 2, ak = (t & 3) * 8;
  u16* AsW = As + (t & ~63) * 8;
  u16* BsW = Bs + (t & ~63) * 8;
  const u16* Ag = A + (size_t)(m0 + ar) * K + ak;
  const u16* Bg = Bt + (size_t)(n0 + ar) * K + ak;

  f32x4 acc[4][4] = {};
  for (int k0 = 0; k0 < K; k0 += 32) {
    __syncthreads();
    GLDS16(Ag + k0, AsW);
    GLDS16(Ag + (size_t)64 * K + k0, AsW + 2048);
    GLDS16(Bg + k0, BsW);
    GLDS16(Bg + (size_t)64 * K + k0, BsW + 2048);
    __syncthreads();
    bf16x8 af[4], bfr[4];
#pragma unroll
    for (int i = 0; i < 4; ++i)
      af[i] = *(const bf16x8*)&As[(wr * 64 + i * 16 + l15) * 32 + g * 8];
#pragma unroll
    for (int j = 0; j < 4; ++j)
      bfr[j] = *(const bf16x8*)&Bs[(wc * 64 + j * 16 + l15) * 32 + g * 8];
#pragma unroll
    for (int i = 0; i < 4; ++i)
#pragma unroll
      for (int j = 0; j < 4; ++j)
        acc[i][j] = MFMA16(af[i], bfr[j], acc[i][j]);
  }

#pragma unroll
  for (int j = 0; j < 4; ++j) {
    const int n = n0 + wc * 64 + j * 16 + l15;
    const float bv = bias[n];
#pragma unroll
    for (int i = 0; i < 4; ++i) {
      const int mbase = m0 + wr * 64 + i * 16 + g * 4;
#pragma unroll
      for (int r = 0; r < 4; ++r) {
        const float v = acc[i][j][r] + bv;
        const int m = mbase + r;
        const int part = n >> 10, f = n & 1023;
        const int hh = f >> 6, d = f & 63;
        const int b = m >> 11, s = m & 2047;
        const size_t off = (((size_t)(b * 16 + hh)) * 2048 + s) * 64 + d;
        u16* dst = (part == 0) ? Qo : (part == 1) ? Ko : Vo;
        dst[off] = f2bf(part == 0 ? v * QSCALE : v);
      }
    }
  }
}

// ---------------- GEMM 64x128 (proj): fp32 out[M][N], +bias -----------------
// grid (M/64, N/128); 4 waves 2x2, wave subtile 32x64
__global__ __launch_bounds__(256) void gemm_proj_kernel(
    const u16* __restrict__ A, const u16* __restrict__ Bt,
    const float* __restrict__ bias, float* __restrict__ outF, int N, int K) {
  __shared__ __align__(16) u16 As[64 * 32];
  __shared__ __align__(16) u16 Bs[128 * 32];
  const int t = threadIdx.x;
  const int lane = t & 63;
  const int l15 = lane & 15, g = lane >> 4;
  const int w = t >> 6, wr = w >> 1, wc = w & 1;
  const int m0 = blockIdx.x * 64, n0 = blockIdx.y * 128;
  const int ar = t >> 2, ak = (t & 3) * 8;
  u16* AsW = As + (t & ~63) * 8;
  u16* BsW = Bs + (t & ~63) * 8;
  const u16* Ag = A + (size_t)(m0 + ar) * K + ak;
  const u16* Bg = Bt + (size_t)(n0 + ar) * K + ak;

  f32x4 acc[2][4] = {};
  for (int k0 = 0; k0 < K; k0 += 32) {
    __syncthreads();
    GLDS16(Ag + k0, AsW);
    GLDS16(Bg + k0, BsW);
    GLDS16(Bg + (size_t)64 * K + k0, BsW + 2048);
    __syncthreads();
    bf16x8 af[2], bfr[4];
#pragma unroll
    for (int i = 0; i < 2; ++i)
      af[i] = *(const bf16x8*)&As[(wr * 32 + i * 16 + l15) * 32 + g * 8];
#pragma unroll
    for (int j = 0; j < 4; ++j)
      bfr[j] = *(const bf16x8*)&Bs[(wc * 64 + j * 16 + l15) * 32 + g * 8];
#pragma unroll
    for (int i = 0; i < 2; ++i)
#pragma unroll
      for (int j = 0; j < 4; ++j)
        acc[i][j] = MFMA16(af[i], bfr[j], acc[i][j]);
  }

#pragma unroll
  for (int j = 0; j < 4; ++j) {
    const int n = n0 + wc * 64 + j * 16 + l15;
    const float bv = bias[n];
#pragma unroll
    for (int i = 0; i < 2; ++i) {
      const int mbase = m0 + wr * 32 + i * 16 + g * 4;
#pragma unroll
      for (int r = 0; r < 4; ++r)
        outF[(size_t)(mbase + r) * N + n] = acc[i][j][r] + bv;
    }
  }
}

// ---------------- flash attention (causal), bf16 MFMA --------------
// grid: (B*H, 32 slots); block 256 (4 waves x 16 q-rows), one q-tile/block.
// Slot->bx map {b,31-b,15-b,16+b} balances each CU's residency quad at 66
// kv-tiles while keeping same-head blocks on one XCD (id mod 8 = bh mod 8).
__global__ __launch_bounds__(256) void attn_kernel(
    const u16* __restrict__ Qg, const u16* __restrict__ Kg,
    const u16* __restrict__ Vg, u16* __restrict__ Og) {
  __shared__ __align__(16) u16 Ks[2][64 * 64];
  __shared__ __align__(16) u16 Vt[2][64 * 72];

  const int bh = blockIdx.x;  // b*16+h
  const int slot = blockIdx.y;
  const int b7 = slot & 7, q2 = slot >> 3;
  const int bx = (q2 == 0) ? b7 : (q2 == 1) ? 31 - b7
                 : (q2 == 2) ? 15 - b7 : 16 + b7;
  const int t = threadIdx.x;
  const int lane = t & 63, w = t >> 6;
  const int l15 = lane & 15, g = (lane >> 4) & 3;
  const bool ghi = (lane & 32) != 0;  // dest g>>1
  // ds_bpermute source-lane byte addresses (source g' = 2(g&1) + (jj>>1))
  const int addrA = (l15 + 16 * ((2 * g) & 3)) << 2;      // for jj<2
  const int addrB = (l15 + 16 * ((2 * g + 1) & 3)) << 2;  // for jj>=2

  const size_t hb = (size_t)bh * (2048 * 64);
  const u16* Qh = Qg + hb;
  const u16* Kh = Kg + hb;
  const u16* Vh = Vg + hb;
  const int b = bh >> 4, h = bh & 15;

  const int kr = t >> 3;         // staging row 8w..8w+7
  const int cs = t & 7;          // staging chunk slot
  const int cl = cs ^ (kr & 7);  // K swizzle: logical chunk for this slot

  const int q0 = bx * 64;
  const int nt = bx + 1;

  const int qrow = q0 + w * 16 + l15;
  const bf16x8 qf0 = *(const bf16x8*)(Qh + (size_t)qrow * 64 + g * 8);
  const bf16x8 qf1 = *(const bf16x8*)(Qh + (size_t)qrow * 64 + 32 + g * 8);

  f32x4 oacc[4] = {};
  float mrow = -1e30f, lrow = 0.f;

  // ---- prologue: stage tile 0 ----
  u16x8 vpre[2];
  {
    u16* KsW = &Ks[0][(t & ~63) * 8];
    GLDS16(Kh + (size_t)kr * 64 + cl * 8, KsW);
    GLDS16(Kh + (size_t)(32 + kr) * 64 + cl * 8, KsW + 2048);
    vpre[0] = *(const u16x8*)(Vh + (size_t)kr * 64 + cs * 8);
    vpre[1] = *(const u16x8*)(Vh + (size_t)(32 + kr) * 64 + cs * 8);
  }
  __syncthreads();  // drains vmcnt: K in LDS, V in regs
#pragma unroll
  for (int i = 0; i < 2; ++i) {
    const int col = ((i * 32 + kr) ^ (cs << 3));
#pragma unroll
    for (int j = 0; j < 8; ++j) Vt[0][(cs * 8 + j) * 72 + col] = vpre[i][j];
  }
  __syncthreads();

  for (int kt = 0; kt < nt; ++kt) {
    const int cur = kt & 1, nxt = cur ^ 1;
    const bool pf = (kt + 1 < nt);
    if (pf) {  // issue next tile's staging; hides under compute below
      const int kv0n = (kt + 1) * 64;
      u16* KsW = &Ks[nxt][(t & ~63) * 8];
      GLDS16(Kh + (size_t)(kv0n + kr) * 64 + cl * 8, KsW);
      GLDS16(Kh + (size_t)(kv0n + 32 + kr) * 64 + cl * 8, KsW + 2048);
      vpre[0] = *(const u16x8*)(Vh + (size_t)(kv0n + kr) * 64 + cs * 8);
      vpre[1] = *(const u16x8*)(Vh + (size_t)(kv0n + 32 + kr) * 64 + cs * 8);
    }

    // S^T = K Q^T : lane holds S[q=qrow][kv = cf*16 + g*4 + r]
    f32x4 sacc[4];
#pragma unroll
    for (int cf = 0; cf < 4; ++cf) {
      const int krow = cf * 16 + l15;
      const int sw = krow & 7;
      const bf16x8 kf0 = *(const bf16x8*)&Ks[cur][krow * 64 + (g ^ sw) * 8];
      const bf16x8 kf1 =
          *(const bf16x8*)&Ks[cur][krow * 64 + ((g + 4) ^ sw) * 8];
      f32x4 z = {0.f, 0.f, 0.f, 0.f};
      z = MFMA16(kf0, qf0, z);
      z = MFMA16(kf1, qf1, z);
      sacc[cf] = z;
    }

    if (kt == bx) {  // diagonal tile: causal mask
      const int kv0 = kt * 64;
#pragma unroll
      for (int cf = 0; cf < 4; ++cf)
#pragma unroll
        for (int r = 0; r < 4; ++r) {
          const int kj = kv0 + cf * 16 + g * 4 + r;
          if (kj > qrow) sacc[cf][r] = -1e30f;
        }
    }

    // online softmax: all 16 kv values for q=qrow are in-lane
    float tm = -1e30f;
#pragma unroll
    for (int cf = 0; cf < 4; ++cf)
#pragma unroll
      for (int r = 0; r < 4; ++r) tm = fmaxf(tm, sacc[cf][r]);
    tm = fmaxf(tm, __shfl_xor(tm, 16));
    tm = fmaxf(tm, __shfl_xor(tm, 32));

    // defer-rescale: when no row's max grew (sc==1 exactly), skip rescale
    if (!__all(tm <= mrow)) {
      const float mn = fmaxf(mrow, tm);
      const float sc = __builtin_amdgcn_exp2f(mrow - mn);
      mrow = mn;
      lrow *= sc;
#pragma unroll
      for (int f = 0; f < 4; ++f) oacc[f] *= sc;
    }

    float rs = 0.f;
#pragma unroll
    for (int cf = 0; cf < 4; ++cf)
#pragma unroll
      for (int r = 0; r < 4; ++r) {
        const float p = __builtin_amdgcn_exp2f(sacc[cf][r] - mrow);
        sacc[cf][r] = p;
        rs += p;
      }
    rs += __shfl_xor(rs, 16);
    rs += __shfl_xor(rs, 32);
    lrow += rs;

    // pack P to bf16 pairs: pk[cf][s] covers kv = 16cf + 4g + 2s + {0,1}
    int pk[4][2];
#pragma unroll
    for (int cf = 0; cf < 4; ++cf)
#pragma unroll
      for (int s = 0; s < 2; ++s) {
        bf16x2 tp = {(__bf16)sacc[cf][2 * s], (__bf16)sacc[cf][2 * s + 1]};
        pk[cf][s] = __builtin_bit_cast(int, tp);
      }

    // redistribute to PV B-frag: bfr[c][jj] = kv pair 32c + 8g + 2jj.
    // Dest lane needs register pk[2c + (dest g>>1)][jj&1] of source lane
    // g' = 2(g&1)+(jj>>1); fetch both cf candidates, post-select by dest ghi.
    int bfr[2][4];
#pragma unroll
    for (int c = 0; c < 2; ++c)
#pragma unroll
      for (int jj = 0; jj < 4; ++jj) {
        const int addr = (jj >> 1) ? addrB : addrA;
        const int vlo = __builtin_amdgcn_ds_bpermute(addr, pk[2 * c][jj & 1]);
        const int vhi =
            __builtin_amdgcn_ds_bpermute(addr, pk[2 * c + 1][jj & 1]);
        bfr[c][jj] = ghi ? vhi : vlo;
      }

    // O^T += V^T P^T
#pragma unroll
    for (int c = 0; c < 2; ++c) {
      const i32x4 bb = {bfr[c][0], bfr[c][1], bfr[c][2], bfr[c][3]};
      const bf16x8 pb = __builtin_bit_cast(bf16x8, bb);
#pragma unroll
      for (int f = 0; f < 4; ++f) {
        const int d = f * 16 + l15;
        const int csw = (c * 32 + g * 8) ^ (((d >> 3) & 7) << 3);
        const bf16x8 va = *(const bf16x8*)&Vt[cur][d * 72 + csw];
        oacc[f] = MFMA16(va, pb, oacc[f]);
      }
    }

    if (pf) {
      __syncthreads();  // all waves done reading Ks/Vt[cur]; vmcnt drained
#pragma unroll
      for (int i = 0; i < 2; ++i) {
        const int col = ((i * 32 + kr) ^ (cs << 3));
#pragma unroll
        for (int j = 0; j < 8; ++j)
          Vt[nxt][(cs * 8 + j) * 72 + col] = vpre[i][j];
      }
      __syncthreads();  // Vt[nxt] visible
    }
  }

  // write merged-head O[b][s][h*64 + d], d = f*16 + g*4 + r
  const float inv = 1.f / lrow;
#pragma unroll
  for (int f = 0; f < 4; ++f) {
    ushort4 o;
    o.x = __builtin_bit_cast(u16, (__bf16)(oacc[f][0] * inv));
    o.y = __builtin_bit_cast(u16, (__bf16)(oacc[f][1] * inv));
    o.z = __builtin_bit_cast(u16, (__bf16)(oacc[f][2] * inv));
    o.w = __builtin_bit_cast(u16, (__bf16)(oacc[f][3] * inv));
    *(ushort4*)&Og[((size_t)b * 2048 + qrow) * 1024 + h * 64 + f * 16 +
                   g * 4] = o;
  }
}

extern "C" void kernel_launch(void* const* d_in, const int* in_sizes, int n_in,
                              void* d_out, int out_size, void* d_ws,
                              size_t ws_size, hipStream_t stream) {
  const float* x = (const float*)d_in[0];       // [2,2048,1024]
  const float* w_attn = (const float*)d_in[1];  // [1024,3072]
  const float* b_attn = (const float*)d_in[2];  // [3072]
  const float* w_proj = (const float*)d_in[3];  // [1024,1024]
  const float* b_proj = (const float*)d_in[4];  // [1024]
  float* out = (float*)d_out;                   // [2,2048,1024] fp32

  char* ws = (char*)d_ws;
  u16* xb = (u16*)(ws);                          // 8 MB (reused as O later)
  u16* wT = (u16*)(ws + (8u << 20));             // 6 MB  [3072][1024]
  u16* wpT = (u16*)(ws + (14u << 20));           // 2 MB  [1024][1024]
  u16* Qb = (u16*)(ws + (16u << 20));            // 8 MB  [b][h][s][d]
  u16* Kb = (u16*)(ws + (24u << 20));            // 8 MB
  u16* Vb = (u16*)(ws + (32u << 20));            // 8 MB
  u16* Ob = xb;                                  // reuse xb region

  convert_x_kernel<<<4096, 256, 0, stream>>>(x, xb, 1048576);
  transpose_w_kernel<<<dim3(96, 32), 256, 0, stream>>>(w_attn, wT, 1024, 3072);
  transpose_w_kernel<<<dim3(32, 32), 256, 0, stream>>>(w_proj, wpT, 1024, 1024);

  gemm_qkv_kernel<<<dim3(32, 24), 256, 0, stream>>>(xb, wT, b_attn, Qb, Kb,
                                                    Vb, 1024);

  attn_kernel<<<dim3(32, 32), 256, 0, stream>>>(Qb, Kb, Vb, Ob);

  gemm_proj_kernel<<<dim3(64, 8), 256, 0, stream>>>(Ob, wpT, b_proj, out,
                                                    1024, 1024);
}